// Round 13
// baseline (125.518 us; speedup 1.0000x reference)
//
#include <hip/hip_runtime.h>

// Chamfer distance, B=4, N=8192, fp32 3-D points, MI355X.
// Round 13: ABLATION ROUND (r5-r12 all hit a ~5x VALU inflation wall that
// theory can't explain; decompose it with per-variant counter rows).
//   V0 = r12 pipeline verbatim (correct output, region 0)
//   V1 = MFMAs only, folds removed, accs kept live via asm (region 1, junk)
//   V2 = folds only, MFMAs replaced by bitcast of ds-loaded frags (region 2)
// All at 2x work (copy bit) so each row clears the ~40us harness fills.

typedef _Float16 half8  __attribute__((ext_vector_type(8)));
typedef float    f32x16 __attribute__((ext_vector_type(16)));
typedef float    f32x4  __attribute__((ext_vector_type(4)));

#define NPTS   8192
#define NB     4
#define SPLITS 8
#define TPW    32
#define QWIN   (TPW * 32)

#define MFMA_V(d, a, b, c)                                             \
    asm("v_mfma_f32_32x32x16_f16 %0, %1, %2, %3"                       \
        : "=&v"(d) : "v"(a), "v"(b), "v"(c))

#define MIN3(dst, s0, s1)                                              \
    asm("v_min3_f32 %0, %1, %2, %0"                                    \
        : "+v"(dst) : "v"(s0), "v"(s1))

#define SB() __builtin_amdgcn_sched_barrier(0)

// ---------- templated main: V = 0 full / 1 nofold / 2 nomfma ----------
template<int V>
__global__ __launch_bounds__(256, 3) void chamfer_main(
    const float* __restrict__ pc1, const float* __restrict__ pc2,
    float* __restrict__ ws_row)
{
    __shared__ half8 Bf[(TPW + 4) * 64];

    int bid = blockIdx.x;
    const int pt   = bid & 31;            bid >>= 5;
    const int qs   = bid & (SPLITS - 1);  bid >>= 3;
    const int b    = bid & (NB - 1);      bid >>= 2;
    const int dir  = bid & 1;             bid >>= 1;
    const int copy = bid;

    const int tid = threadIdx.x;
    const int w = tid >> 6, lane = tid & 63;
    const int col = lane & 31, g = lane >> 5;
    const int pbase = pt * 256 + w * 64;

    const float* Acl = dir ? pc2 : pc1;
    const float* Bcl = dir ? pc1 : pc2;

    const _Float16 one = (_Float16)1.0f, zz = (_Float16)0.0f;

    for (int i = tid; i < QWIN; i += 256) {
        const int t = i >> 5, c = i & 31;
        const float* Q = Bcl + ((size_t)b * NPTS + qs * QWIN + i) * 3;
        const float qx = Q[0], qy = Q[1], qz = Q[2];

        const _Float16 hx = (_Float16)qx, hy = (_Float16)qy, hz = (_Float16)qz;
        const _Float16 lx = (_Float16)(qx - (float)hx);
        const _Float16 ly = (_Float16)(qy - (float)hy);
        const _Float16 lz = (_Float16)(qz - (float)hz);
        const float sq = fmaf(qx, qx, fmaf(qy, qy, qz * qz));
        const _Float16 sh = (_Float16)sq;
        const _Float16 sl = (_Float16)(sq - (float)sh);

        const _Float16 nhx = (_Float16)(-2.0f * (float)hx);
        const _Float16 nhy = (_Float16)(-2.0f * (float)hy);
        const _Float16 nhz = (_Float16)(-2.0f * (float)hz);
        const _Float16 nlx = (_Float16)(-2.0f * (float)lx);
        const _Float16 nly = (_Float16)(-2.0f * (float)ly);
        const _Float16 nlz = (_Float16)(-2.0f * (float)lz);

        Bf[t * 64 + c]      = (half8){nhx, nhy, nhz, nlx, nly, nlz, nhx, nhy};
        Bf[t * 64 + 32 + c] = (half8){nhz, one, one, sh,  sl,  zz,  zz,  zz};
    }

    half8 a0, a1;
    #pragma unroll
    for (int h = 0; h < 2; ++h) {
        const float* P = Acl + ((size_t)b * NPTS + pbase + h * 32 + col) * 3;
        const float px = P[0], py = P[1], pz = P[2];
        const _Float16 hx = (_Float16)px, hy = (_Float16)py, hz = (_Float16)pz;
        const _Float16 lx = (_Float16)(px - (float)hx);
        const _Float16 ly = (_Float16)(py - (float)hy);
        const _Float16 lz = (_Float16)(pz - (float)hz);
        const float sq1 = fmaf(px, px, fmaf(py, py, pz * pz));
        const _Float16 sh = (_Float16)sq1;
        const _Float16 sl = (_Float16)(sq1 - (float)sh);
        half8 a;
        if (g == 0) a = (half8){hx, hy, hz, hx, hy, hz, lx, ly};
        else        a = (half8){lz, sh, sl, one, one, zz, zz, zz};
        if (h == 0) a0 = a; else a1 = a;
    }

    float rm0[16], rm1[16];
    #pragma unroll
    for (int r = 0; r < 16; ++r) { rm0[r] = 3.402823466e+38f;
                                   rm1[r] = 3.402823466e+38f; }
    f32x16 zero16;
    #pragma unroll
    for (int r = 0; r < 16; ++r) zero16[r] = 0.0f;

    __syncthreads();

    half8 p0 = Bf[0 * 64 + lane], p1 = Bf[1 * 64 + lane];
    half8 p2 = Bf[2 * 64 + lane], p3 = Bf[3 * 64 + lane];

    if constexpr (V == 0) {
        // ---------------- V0: full r12 pipeline ----------------
        f32x16 accA0, accA1, accB0, accB1;
        {
            const half8 m0 = Bf[4 * 64 + lane];
            const half8 m1 = Bf[5 * 64 + lane];
            MFMA_V(accA0, a0, p0, zero16);
            MFMA_V(accA1, a0, p1, zero16);
            SB();
            MFMA_V(accB0, a1, p0, zero16);
            MFMA_V(accB1, a1, p1, zero16);
            SB();
            #pragma unroll
            for (int r = 0; r < 16; ++r) MIN3(rm0[r], accA0[r], accA1[r]);
            SB();
            p0 = p2; p1 = p3; p2 = m0; p3 = m1;
        }
        #pragma unroll 2
        for (int i = 1; i < TPW / 2; ++i) {
            const half8 m0 = Bf[(2 * i + 4) * 64 + lane];
            const half8 m1 = Bf[(2 * i + 5) * 64 + lane];
            MFMA_V(accA0, a0, p0, zero16);
            MFMA_V(accA1, a0, p1, zero16);
            SB();
            #pragma unroll
            for (int r = 0; r < 16; ++r) MIN3(rm1[r], accB0[r], accB1[r]);
            SB();
            MFMA_V(accB0, a1, p0, zero16);
            MFMA_V(accB1, a1, p1, zero16);
            SB();
            #pragma unroll
            for (int r = 0; r < 16; ++r) MIN3(rm0[r], accA0[r], accA1[r]);
            SB();
            p0 = p2; p1 = p3; p2 = m0; p3 = m1;
        }
        #pragma unroll
        for (int r = 0; r < 16; ++r) MIN3(rm1[r], accB0[r], accB1[r]);
    } else if constexpr (V == 1) {
        // ---------------- V1: MFMAs only, folds removed ----------------
        #pragma unroll 2
        for (int i = 0; i < TPW / 2; ++i) {
            const half8 m0 = Bf[(2 * i + 4) * 64 + lane];
            const half8 m1 = Bf[(2 * i + 5) * 64 + lane];
            f32x16 accA0, accA1, accB0, accB1;
            MFMA_V(accA0, a0, p0, zero16);
            MFMA_V(accA1, a0, p1, zero16);
            MFMA_V(accB0, a1, p0, zero16);
            MFMA_V(accB1, a1, p1, zero16);
            SB();
            asm volatile("" :: "v"(accA0), "v"(accA1), "v"(accB0), "v"(accB1));
            SB();
            p0 = p2; p1 = p3; p2 = m0; p3 = m1;
        }
    } else {
        // ---------------- V2: folds only, no MFMA (bitcast inputs) --------
        #pragma unroll 2
        for (int i = 0; i < TPW / 2; ++i) {
            const half8 m0 = Bf[(2 * i + 4) * 64 + lane];
            const half8 m1 = Bf[(2 * i + 5) * 64 + lane];
            const f32x4 f0 = __builtin_bit_cast(f32x4, p0);
            const f32x4 f1 = __builtin_bit_cast(f32x4, p1);
            const f32x4 f2 = __builtin_bit_cast(f32x4, p2);
            const f32x4 f3 = __builtin_bit_cast(f32x4, p3);
            SB();
            #pragma unroll
            for (int r = 0; r < 16; ++r) MIN3(rm1[r], f0[r & 3], f1[r & 3]);
            SB();
            #pragma unroll
            for (int r = 0; r < 16; ++r) MIN3(rm0[r], f2[r & 3], f3[r & 3]);
            SB();
            p0 = p2; p1 = p3; p2 = m0; p3 = m1;
        }
    }

    // ---- cross-column min + store ----
    const size_t region = (size_t)V * 2 + copy;           // V0 copy0 = region 0
    const size_t obase =
        ((region * 2 + dir) * NB + b) * SPLITS * (size_t)NPTS
        + (size_t)qs * NPTS + pbase;
    #pragma unroll
    for (int r = 0; r < 16; ++r) {
        float v = rm0[r];
        v = fminf(v, __shfl_xor(v, 1, 64));
        v = fminf(v, __shfl_xor(v, 2, 64));
        v = fminf(v, __shfl_xor(v, 4, 64));
        v = fminf(v, __shfl_xor(v, 8, 64));
        v = fminf(v, __shfl_xor(v, 16, 64));
        float u = rm1[r];
        u = fminf(u, __shfl_xor(u, 1, 64));
        u = fminf(u, __shfl_xor(u, 2, 64));
        u = fminf(u, __shfl_xor(u, 4, 64));
        u = fminf(u, __shfl_xor(u, 8, 64));
        u = fminf(u, __shfl_xor(u, 16, 64));
        if (col == 0) {
            const int row = (r & 3) + 8 * (r >> 2) + 4 * g;
            ws_row[obase + row]      = v;
            ws_row[obase + 32 + row] = u;
        }
    }
}

// ---------- reduce: reads region 0 (V0, copy 0) only ----------
__global__ __launch_bounds__(256) void chamfer_reduce(
    const float* __restrict__ ws_row, float* __restrict__ partial)
{
    int bid = blockIdx.x;
    const int sl  = bid & 31; bid >>= 5;
    const int b   = bid & 3;  bid >>= 2;
    const int dir = bid;

    const int p = sl * 256 + threadIdx.x;
    const float* base = ws_row + (((size_t)dir * NB + b) * SPLITS) * NPTS + p;
    float m0 = fminf(base[0],        base[NPTS]);
    float m1 = fminf(base[2 * NPTS], base[3 * NPTS]);
    float m2 = fminf(base[4 * NPTS], base[5 * NPTS]);
    float m3 = fminf(base[6 * NPTS], base[7 * NPTS]);
    float sum = fminf(fminf(m0, m1), fminf(m2, m3));

    for (int off = 32; off; off >>= 1) sum += __shfl_down(sum, off, 64);
    __shared__ float red[4];
    if (!(threadIdx.x & 63)) red[threadIdx.x >> 6] = sum;
    __syncthreads();
    if (!threadIdx.x)
        partial[blockIdx.x] = red[0] + red[1] + red[2] + red[3];
}

__global__ __launch_bounds__(64) void chamfer_final(
    const float* __restrict__ partial, float* __restrict__ out)
{
    const int b = blockIdx.x, t = threadIdx.x;
    const int dir = t >> 5, sl = t & 31;
    float v = partial[(((size_t)dir * NB + b) << 5) + sl];
    for (int off = 32; off; off >>= 1) v += __shfl_down(v, off, 64);
    if (!t) out[b] = v * (1.0f / (float)NPTS);
}

extern "C" void kernel_launch(void* const* d_in, const int* in_sizes, int n_in,
                              void* d_out, int out_size, void* d_ws, size_t ws_size,
                              hipStream_t stream)
{
    const float* pc1 = (const float*)d_in[0];
    const float* pc2 = (const float*)d_in[1];
    float* out = (float*)d_out;

    char* ws = (char*)d_ws;
    float* ws_row  = (float*)ws;                 // 6 regions x 2 MiB = 12 MiB
    float* partial = (float*)(ws + (12 << 20));  // 1 KiB

    chamfer_main<0><<<4096, 256, 0, stream>>>(pc1, pc2, ws_row);
    chamfer_main<1><<<4096, 256, 0, stream>>>(pc1, pc2, ws_row);
    chamfer_main<2><<<4096, 256, 0, stream>>>(pc1, pc2, ws_row);
    chamfer_reduce<<<256, 256, 0, stream>>>(ws_row, partial);
    chamfer_final<<<NB, 64, 0, stream>>>(partial, out);
}

// Round 15
// 40.247 us; speedup vs baseline: 3.1187x; 3.1187x over previous
//
#include <hip/hip_runtime.h>

// Chamfer distance, B=4, N=8192, fp32 3-D points, MI355X.
// Round 15: r14 (small live set: ONE A-frag/wave, 2 MFMA + fold per iter)
// + RESTORED MFMA->VALU hazard wall (r14 deleted it -> absmax 9920; inline
// asm MFMA has no compiler-inserted wait states; VGPR-dest MFMA needs ~17
// wait states before a VALU read). Pattern proven correct in r11.
//   per iter: 2 ds_read_b128 + 2 MFMA + 19cyc nop wall + 16 v_min3
//   live ~100 regs (acc 32 + rm 16 + ring 16 + zero16 16 + a 8 + misc)
//   -> tests the r13 theory that ~154-reg live sets trigger AGPR homing +
//      v_accvgpr shuttle (the ~3x VALU inflation seen r5-r13)
// K-slot packing (verified r3-r13):
//   A g0={hx,hy,hz,hx,hy,hz,lx,ly}  g1={lz,sh,sl,1,1,0,0,0}
//   B g0={-2hx,-2hy,-2hz,-2lx,-2ly,-2lz,-2hx,-2hy}  g1={-2hz,1,1,sh,sl,0,0,0}

typedef _Float16 half8  __attribute__((ext_vector_type(8)));
typedef float    f32x16 __attribute__((ext_vector_type(16)));

#define NPTS   8192
#define NB     4
#define SPLITS 8
#define TPW    32                  // B-tiles per window
#define QWIN   (TPW * 32)          // 1024 q-points per window

#define MFMA_V(d, a, b, c)                                             \
    asm("v_mfma_f32_32x32x16_f16 %0, %1, %2, %3"                       \
        : "=&v"(d) : "v"(a), "v"(b), "v"(c))

#define MIN3(dst, s0, s1)                                              \
    asm("v_min3_f32 %0, %1, %2, %0"                                    \
        : "+v"(dst) : "v"(s0), "v"(s1))

#define SB() __builtin_amdgcn_sched_barrier(0)

// ---------- main: 4096 blocks x 256 thr (4 waves) ----------
// block = (dir, b, qsplit-of-8, ptile-of-128); wave = 32 p-rows (1 A-tile).
__global__ __launch_bounds__(256) void chamfer_main(
    const float* __restrict__ pc1, const float* __restrict__ pc2,
    float* __restrict__ ws_row)
{
    __shared__ half8 Bf[(TPW + 2) * 64];   // +2 pad tiles for prefetch tail

    int bid = blockIdx.x;
    const int pt  = bid & 63;            bid >>= 6;
    const int qs  = bid & (SPLITS - 1);  bid >>= 3;
    const int b   = bid & (NB - 1);      bid >>= 2;
    const int dir = bid;

    const int tid = threadIdx.x;
    const int w = tid >> 6, lane = tid & 63;
    const int col = lane & 31, g = lane >> 5;
    const int pbase = pt * 128 + w * 32;       // this wave: rows pbase..pbase+31

    const float* Acl = dir ? pc2 : pc1;        // row side
    const float* Bcl = dir ? pc1 : pc2;        // col side

    const _Float16 one = (_Float16)1.0f, zz = (_Float16)0.0f;

    // ---- build this block's B-fragment window in LDS (4 points/thread) ----
    for (int i = tid; i < QWIN; i += 256) {
        const int t = i >> 5, c = i & 31;
        const float* Q = Bcl + ((size_t)b * NPTS + qs * QWIN + i) * 3;
        const float qx = Q[0], qy = Q[1], qz = Q[2];

        const _Float16 hx = (_Float16)qx, hy = (_Float16)qy, hz = (_Float16)qz;
        const _Float16 lx = (_Float16)(qx - (float)hx);
        const _Float16 ly = (_Float16)(qy - (float)hy);
        const _Float16 lz = (_Float16)(qz - (float)hz);
        const float sq = fmaf(qx, qx, fmaf(qy, qy, qz * qz));
        const _Float16 sh = (_Float16)sq;
        const _Float16 sl = (_Float16)(sq - (float)sh);

        const _Float16 nhx = (_Float16)(-2.0f * (float)hx);
        const _Float16 nhy = (_Float16)(-2.0f * (float)hy);
        const _Float16 nhz = (_Float16)(-2.0f * (float)hz);
        const _Float16 nlx = (_Float16)(-2.0f * (float)lx);
        const _Float16 nly = (_Float16)(-2.0f * (float)ly);
        const _Float16 nlz = (_Float16)(-2.0f * (float)lz);

        Bf[t * 64 + c]      = (half8){nhx, nhy, nhz, nlx, nly, nlz, nhx, nhy};
        Bf[t * 64 + 32 + c] = (half8){nhz, one, one, sh,  sl,  zz,  zz,  zz};
    }

    // ---- ONE A fragment (rows pbase+col) ----
    half8 a0;
    {
        const float* P = Acl + ((size_t)b * NPTS + pbase + col) * 3;
        const float px = P[0], py = P[1], pz = P[2];
        const _Float16 hx = (_Float16)px, hy = (_Float16)py, hz = (_Float16)pz;
        const _Float16 lx = (_Float16)(px - (float)hx);
        const _Float16 ly = (_Float16)(py - (float)hy);
        const _Float16 lz = (_Float16)(pz - (float)hz);
        const float sq1 = fmaf(px, px, fmaf(py, py, pz * pz));
        const _Float16 sh = (_Float16)sq1;
        const _Float16 sl = (_Float16)(sq1 - (float)sh);
        if (g == 0) a0 = (half8){hx, hy, hz, hx, hy, hz, lx, ly};
        else        a0 = (half8){lz, sh, sl, one, one, zz, zz, zz};
    }

    float rm[16];
    #pragma unroll
    for (int r = 0; r < 16; ++r) rm[r] = 3.402823466e+38f;
    f32x16 zero16;
    #pragma unroll
    for (int r = 0; r < 16; ++r) zero16[r] = 0.0f;

    __syncthreads();   // LDS build complete; read-only from here on

    half8 p0 = Bf[0 * 64 + lane], p1 = Bf[1 * 64 + lane];

    #pragma unroll 2
    for (int t = 0; t < TPW; t += 2) {
        // prefetch next pair (tail lands in the 2 pad tiles, never consumed)
        const half8 m0 = Bf[(t + 2) * 64 + lane];
        const half8 m1 = Bf[(t + 3) * 64 + lane];

        f32x16 acc0, acc1;
        MFMA_V(acc0, a0, p0, zero16);
        MFMA_V(acc1, a0, p1, zero16);
        SB();
        // MFMA->VALU hazard wall: 19 wait states after the last MFMA issue
        // before any VALU read of acc (r14 omitted this -> garbage folds)
        asm volatile("s_nop 7\n\ts_nop 7\n\ts_nop 3");
        SB();
        #pragma unroll
        for (int r = 0; r < 16; ++r) MIN3(rm[r], acc0[r], acc1[r]);
        SB();

        p0 = m0; p1 = m1;
    }

    // ---- cross-column min (32 cols) + store; row map (r&3)+8*(r>>2)+4*g ----
    const size_t obase = (((size_t)dir * NB + b) * SPLITS + qs) * NPTS + pbase;
    #pragma unroll
    for (int r = 0; r < 16; ++r) {
        float v = rm[r];
        v = fminf(v, __shfl_xor(v, 1, 64));
        v = fminf(v, __shfl_xor(v, 2, 64));
        v = fminf(v, __shfl_xor(v, 4, 64));
        v = fminf(v, __shfl_xor(v, 8, 64));
        v = fminf(v, __shfl_xor(v, 16, 64));
        if (col == 0) {
            const int row = (r & 3) + 8 * (r >> 2) + 4 * g;
            ws_row[obase + row] = v;
        }
    }
}

// ---------- reduce: 256 blocks; min over 8 splits, block partial sums ----------
__global__ __launch_bounds__(256) void chamfer_reduce(
    const float* __restrict__ ws_row, float* __restrict__ partial)
{
    int bid = blockIdx.x;                    // 2 dir x 4 b x 32 slices
    const int sl  = bid & 31; bid >>= 5;
    const int b   = bid & 3;  bid >>= 2;
    const int dir = bid;

    const int p = sl * 256 + threadIdx.x;
    const float* base = ws_row + (((size_t)dir * NB + b) * SPLITS) * NPTS + p;
    float m0 = fminf(base[0],        base[NPTS]);
    float m1 = fminf(base[2 * NPTS], base[3 * NPTS]);
    float m2 = fminf(base[4 * NPTS], base[5 * NPTS]);
    float m3 = fminf(base[6 * NPTS], base[7 * NPTS]);
    float sum = fminf(fminf(m0, m1), fminf(m2, m3));

    for (int off = 32; off; off >>= 1) sum += __shfl_down(sum, off, 64);
    __shared__ float red[4];
    if (!(threadIdx.x & 63)) red[threadIdx.x >> 6] = sum;
    __syncthreads();
    if (!threadIdx.x)
        partial[blockIdx.x] = red[0] + red[1] + red[2] + red[3];
}

// ---------- final: 4 blocks x 64 thr; each b sums its 64 partials ----------
__global__ __launch_bounds__(64) void chamfer_final(
    const float* __restrict__ partial, float* __restrict__ out)
{
    const int b = blockIdx.x, t = threadIdx.x;
    const int dir = t >> 5, sl = t & 31;
    float v = partial[(((size_t)dir * NB + b) << 5) + sl];
    for (int off = 32; off; off >>= 1) v += __shfl_down(v, off, 64);
    if (!t) out[b] = v * (1.0f / (float)NPTS);
}

extern "C" void kernel_launch(void* const* d_in, const int* in_sizes, int n_in,
                              void* d_out, int out_size, void* d_ws, size_t ws_size,
                              hipStream_t stream)
{
    const float* pc1 = (const float*)d_in[0];
    const float* pc2 = (const float*)d_in[1];
    float* out = (float*)d_out;

    char* ws = (char*)d_ws;
    float* ws_row  = (float*)ws;                // 2*4*8*8192*4B = 2 MiB
    float* partial = (float*)(ws + (2 << 20));  // 1 KiB

    chamfer_main<<<4096, 256, 0, stream>>>(pc1, pc2, ws_row);
    chamfer_reduce<<<256, 256, 0, stream>>>(ws_row, partial);
    chamfer_final<<<NB, 64, 0, stream>>>(partial, out);
}

// Round 16
// 39.861 us; speedup vs baseline: 3.1489x; 1.0097x over previous
//
#include <hip/hip_runtime.h>

// Chamfer distance, B=4, N=8192, fp32 3-D points, MI355X.
// Round 16: r15 minus the AGPR-shuttled operands. r15 counters localized the
// ~3.4x VALU inflation (169 vs ~50 cyc/iter): VGPR_Count=52 = exactly
// acc0+acc1+rm+a0 -> zero16 (MFMA C operand) and the 4-frag ring lived in
// AGPRs, and the compiler emitted v_accvgpr_read shuttles before EVERY
// inline-asm MFMA/fold. Fixes:
//   1. MFMA C operand = inline constant 0 in the asm (src2=0 encodable);
//      zero16 deleted entirely.
//   2. ring -> unroll-2 positional double-buffer (pA/pB): no v_mov copies;
//      next pair's ds_reads issue during this pair's fold (latency cover).
//   3. hazard wall (19 wait states) kept -- r14 proved it's required.
// K-slot packing (verified r3-r15):
//   A g0={hx,hy,hz,hx,hy,hz,lx,ly}  g1={lz,sh,sl,1,1,0,0,0}
//   B g0={-2hx,-2hy,-2hz,-2lx,-2ly,-2lz,-2hx,-2hy}  g1={-2hz,1,1,sh,sl,0,0,0}

typedef _Float16 half8  __attribute__((ext_vector_type(8)));
typedef float    f32x16 __attribute__((ext_vector_type(16)));

#define NPTS   8192
#define NB     4
#define SPLITS 8
#define TPW    32                  // B-tiles per window
#define QWIN   (TPW * 32)          // 1024 q-points per window

#define MFMA_Z(d, a, b)                                                \
    asm("v_mfma_f32_32x32x16_f16 %0, %1, %2, 0"                        \
        : "=&v"(d) : "v"(a), "v"(b))

#define MIN3(dst, s0, s1)                                              \
    asm("v_min3_f32 %0, %1, %2, %0"                                    \
        : "+v"(dst) : "v"(s0), "v"(s1))

#define SB() __builtin_amdgcn_sched_barrier(0)

// one MFMA pair + hazard wall + fold
#define STEP(q0, q1)                                                   \
    do {                                                               \
        f32x16 acc0, acc1;                                             \
        MFMA_Z(acc0, a0, q0);                                          \
        MFMA_Z(acc1, a0, q1);                                          \
        SB();                                                          \
        asm volatile("s_nop 7\n\ts_nop 7\n\ts_nop 3");                 \
        SB();                                                          \
        _Pragma("unroll")                                              \
        for (int r = 0; r < 16; ++r) MIN3(rm[r], acc0[r], acc1[r]);    \
        SB();                                                          \
    } while (0)

// ---------- main: 4096 blocks x 256 thr (4 waves) ----------
// block = (dir, b, qsplit-of-8, ptile-of-128); wave = 32 p-rows (1 A-tile).
__global__ __launch_bounds__(256) void chamfer_main(
    const float* __restrict__ pc1, const float* __restrict__ pc2,
    float* __restrict__ ws_row)
{
    __shared__ half8 Bf[(TPW + 2) * 64];   // +2 pad tiles for prefetch tail

    int bid = blockIdx.x;
    const int pt  = bid & 63;            bid >>= 6;
    const int qs  = bid & (SPLITS - 1);  bid >>= 3;
    const int b   = bid & (NB - 1);      bid >>= 2;
    const int dir = bid;

    const int tid = threadIdx.x;
    const int w = tid >> 6, lane = tid & 63;
    const int col = lane & 31, g = lane >> 5;
    const int pbase = pt * 128 + w * 32;       // this wave: rows pbase..pbase+31

    const float* Acl = dir ? pc2 : pc1;        // row side
    const float* Bcl = dir ? pc1 : pc2;        // col side

    const _Float16 one = (_Float16)1.0f, zz = (_Float16)0.0f;

    // ---- build this block's B-fragment window in LDS (4 points/thread) ----
    for (int i = tid; i < QWIN; i += 256) {
        const int t = i >> 5, c = i & 31;
        const float* Q = Bcl + ((size_t)b * NPTS + qs * QWIN + i) * 3;
        const float qx = Q[0], qy = Q[1], qz = Q[2];

        const _Float16 hx = (_Float16)qx, hy = (_Float16)qy, hz = (_Float16)qz;
        const _Float16 lx = (_Float16)(qx - (float)hx);
        const _Float16 ly = (_Float16)(qy - (float)hy);
        const _Float16 lz = (_Float16)(qz - (float)hz);
        const float sq = fmaf(qx, qx, fmaf(qy, qy, qz * qz));
        const _Float16 sh = (_Float16)sq;
        const _Float16 sl = (_Float16)(sq - (float)sh);

        const _Float16 nhx = (_Float16)(-2.0f * (float)hx);
        const _Float16 nhy = (_Float16)(-2.0f * (float)hy);
        const _Float16 nhz = (_Float16)(-2.0f * (float)hz);
        const _Float16 nlx = (_Float16)(-2.0f * (float)lx);
        const _Float16 nly = (_Float16)(-2.0f * (float)ly);
        const _Float16 nlz = (_Float16)(-2.0f * (float)lz);

        Bf[t * 64 + c]      = (half8){nhx, nhy, nhz, nlx, nly, nlz, nhx, nhy};
        Bf[t * 64 + 32 + c] = (half8){nhz, one, one, sh,  sl,  zz,  zz,  zz};
    }

    // ---- ONE A fragment (rows pbase+col) ----
    half8 a0;
    {
        const float* P = Acl + ((size_t)b * NPTS + pbase + col) * 3;
        const float px = P[0], py = P[1], pz = P[2];
        const _Float16 hx = (_Float16)px, hy = (_Float16)py, hz = (_Float16)pz;
        const _Float16 lx = (_Float16)(px - (float)hx);
        const _Float16 ly = (_Float16)(py - (float)hy);
        const _Float16 lz = (_Float16)(pz - (float)hz);
        const float sq1 = fmaf(px, px, fmaf(py, py, pz * pz));
        const _Float16 sh = (_Float16)sq1;
        const _Float16 sl = (_Float16)(sq1 - (float)sh);
        if (g == 0) a0 = (half8){hx, hy, hz, hx, hy, hz, lx, ly};
        else        a0 = (half8){lz, sh, sl, one, one, zz, zz, zz};
    }

    float rm[16];
    #pragma unroll
    for (int r = 0; r < 16; ++r) rm[r] = 3.402823466e+38f;

    __syncthreads();   // LDS build complete; read-only from here on

    // ---- unroll-2 positional double buffer: no ring movs ----
    half8 pA0 = Bf[0 * 64 + lane], pA1 = Bf[1 * 64 + lane];
    half8 pB0, pB1;

    for (int t = 0; t < TPW; t += 4) {
        pB0 = Bf[(t + 2) * 64 + lane];     // prefetch during A's step
        pB1 = Bf[(t + 3) * 64 + lane];
        STEP(pA0, pA1);
        pA0 = Bf[(t + 4) * 64 + lane];     // prefetch during B's step
        pA1 = Bf[(t + 5) * 64 + lane];     // (tail lands in the 2 pad tiles)
        STEP(pB0, pB1);
    }

    // ---- cross-column min (32 cols) + store; row map (r&3)+8*(r>>2)+4*g ----
    const size_t obase = (((size_t)dir * NB + b) * SPLITS + qs) * NPTS + pbase;
    #pragma unroll
    for (int r = 0; r < 16; ++r) {
        float v = rm[r];
        v = fminf(v, __shfl_xor(v, 1, 64));
        v = fminf(v, __shfl_xor(v, 2, 64));
        v = fminf(v, __shfl_xor(v, 4, 64));
        v = fminf(v, __shfl_xor(v, 8, 64));
        v = fminf(v, __shfl_xor(v, 16, 64));
        if (col == 0) {
            const int row = (r & 3) + 8 * (r >> 2) + 4 * g;
            ws_row[obase + row] = v;
        }
    }
}

// ---------- reduce: 256 blocks; min over 8 splits, block partial sums ----------
__global__ __launch_bounds__(256) void chamfer_reduce(
    const float* __restrict__ ws_row, float* __restrict__ partial)
{
    int bid = blockIdx.x;                    // 2 dir x 4 b x 32 slices
    const int sl  = bid & 31; bid >>= 5;
    const int b   = bid & 3;  bid >>= 2;
    const int dir = bid;

    const int p = sl * 256 + threadIdx.x;
    const float* base = ws_row + (((size_t)dir * NB + b) * SPLITS) * NPTS + p;
    float m0 = fminf(base[0],        base[NPTS]);
    float m1 = fminf(base[2 * NPTS], base[3 * NPTS]);
    float m2 = fminf(base[4 * NPTS], base[5 * NPTS]);
    float m3 = fminf(base[6 * NPTS], base[7 * NPTS]);
    float sum = fminf(fminf(m0, m1), fminf(m2, m3));

    for (int off = 32; off; off >>= 1) sum += __shfl_down(sum, off, 64);
    __shared__ float red[4];
    if (!(threadIdx.x & 63)) red[threadIdx.x >> 6] = sum;
    __syncthreads();
    if (!threadIdx.x)
        partial[blockIdx.x] = red[0] + red[1] + red[2] + red[3];
}

// ---------- final: 4 blocks x 64 thr; each b sums its 64 partials ----------
__global__ __launch_bounds__(64) void chamfer_final(
    const float* __restrict__ partial, float* __restrict__ out)
{
    const int b = blockIdx.x, t = threadIdx.x;
    const int dir = t >> 5, sl = t & 31;
    float v = partial[(((size_t)dir * NB + b) << 5) + sl];
    for (int off = 32; off; off >>= 1) v += __shfl_down(v, off, 64);
    if (!t) out[b] = v * (1.0f / (float)NPTS);
}

extern "C" void kernel_launch(void* const* d_in, const int* in_sizes, int n_in,
                              void* d_out, int out_size, void* d_ws, size_t ws_size,
                              hipStream_t stream)
{
    const float* pc1 = (const float*)d_in[0];
    const float* pc2 = (const float*)d_in[1];
    float* out = (float*)d_out;

    char* ws = (char*)d_ws;
    float* ws_row  = (float*)ws;                // 2*4*8*8192*4B = 2 MiB
    float* partial = (float*)(ws + (2 << 20));  // 1 KiB

    chamfer_main<<<4096, 256, 0, stream>>>(pc1, pc2, ws_row);
    chamfer_reduce<<<256, 256, 0, stream>>>(ws_row, partial);
    chamfer_final<<<NB, 64, 0, stream>>>(partial, out);
}

// Round 17
// 27.756 us; speedup vs baseline: 4.5222x; 1.4361x over previous
//
#include <hip/hip_runtime.h>

// Chamfer distance, B=4, N=8192, fp32 3-D points, MI355X.
// Round 17: attack the DS pipe (the model that retrodicts r9 vs r16):
//  - 2 A-frags/wave (64 rows): each B-pair ds_read feeds 4 MFMAs (halves
//    B-read DS traffic per MFMA vs r15/r16)
//  - epilogue: LDS write + block min-reduce + COALESCED store, replacing
//    the 5-step shfl_xor x16 (ds_bpermute storm ~400 DS-clk/wave, ~12us/CU
//    at r16 wave counts -- never addressed before)
//  - sub-step folds: only 2 acc tuples live (r12's 4-acc spill trap avoided)
//  - keep: hazard wall (r14), inline-0 C operand, positional dbuf, TPW=32
// K-slot packing (verified r3-r16):
//   A g0={hx,hy,hz,hx,hy,hz,lx,ly}  g1={lz,sh,sl,1,1,0,0,0}
//   B g0={-2hx,-2hy,-2hz,-2lx,-2ly,-2lz,-2hx,-2hy}  g1={-2hz,1,1,sh,sl,0,0,0}

typedef _Float16 half8  __attribute__((ext_vector_type(8)));
typedef float    f32x16 __attribute__((ext_vector_type(16)));

#define NPTS   8192
#define NB     4
#define SPLITS 8
#define TPW    32                  // B-tiles per window
#define QWIN   (TPW * 32)          // 1024 q-points per window

#define MFMA_Z(d, a, b)                                                \
    asm("v_mfma_f32_32x32x16_f16 %0, %1, %2, 0"                        \
        : "=&v"(d) : "v"(a), "v"(b))

#define MIN3(dst, s0, s1)                                              \
    asm("v_min3_f32 %0, %1, %2, %0"                                    \
        : "+v"(dst) : "v"(s0), "v"(s1))

#define SB() __builtin_amdgcn_sched_barrier(0)

// one B-pair vs both A-frags; 2 acc tuples live at a time
#define STEP2(q0, q1)                                                  \
    do {                                                               \
        {                                                              \
            f32x16 acc0, acc1;                                         \
            MFMA_Z(acc0, a0, q0);                                      \
            MFMA_Z(acc1, a0, q1);                                      \
            SB();                                                      \
            asm volatile("s_nop 7\n\ts_nop 7\n\ts_nop 3");             \
            SB();                                                      \
            _Pragma("unroll")                                          \
            for (int r = 0; r < 16; ++r) MIN3(rm0[r], acc0[r], acc1[r]); \
            SB();                                                      \
        }                                                              \
        {                                                              \
            f32x16 acc0, acc1;                                         \
            MFMA_Z(acc0, a1, q0);                                      \
            MFMA_Z(acc1, a1, q1);                                      \
            SB();                                                      \
            asm volatile("s_nop 7\n\ts_nop 7\n\ts_nop 3");             \
            SB();                                                      \
            _Pragma("unroll")                                          \
            for (int r = 0; r < 16; ++r) MIN3(rm1[r], acc0[r], acc1[r]); \
            SB();                                                      \
        }                                                              \
    } while (0)

// ---------- main: 2048 blocks x 256 thr (4 waves) ----------
// block = (dir, b, qsplit-of-8, ptile-of-256); wave = 64 p-rows (2 A-tiles).
__global__ __launch_bounds__(256) void chamfer_main(
    const float* __restrict__ pc1, const float* __restrict__ pc2,
    float* __restrict__ ws_row)
{
    // Bf: 34 KiB fragment window; after the inner loop (barrier) the same
    // space is reused as the 32 KiB reduction buffer RB[(w*2+h)*16+r][lane].
    __shared__ half8 Bf[(TPW + 2) * 64];

    int bid = blockIdx.x;
    const int pt  = bid & 31;            bid >>= 5;
    const int qs  = bid & (SPLITS - 1);  bid >>= 3;
    const int b   = bid & (NB - 1);      bid >>= 2;
    const int dir = bid;

    const int tid = threadIdx.x;
    const int w = tid >> 6, lane = tid & 63;
    const int col = lane & 31, g = lane >> 5;
    const int pbase = pt * 256 + w * 64;       // this wave: rows pbase..pbase+63

    const float* Acl = dir ? pc2 : pc1;        // row side
    const float* Bcl = dir ? pc1 : pc2;        // col side

    const _Float16 one = (_Float16)1.0f, zz = (_Float16)0.0f;

    // ---- build this block's B-fragment window in LDS (4 points/thread) ----
    for (int i = tid; i < QWIN; i += 256) {
        const int t = i >> 5, c = i & 31;
        const float* Q = Bcl + ((size_t)b * NPTS + qs * QWIN + i) * 3;
        const float qx = Q[0], qy = Q[1], qz = Q[2];

        const _Float16 hx = (_Float16)qx, hy = (_Float16)qy, hz = (_Float16)qz;
        const _Float16 lx = (_Float16)(qx - (float)hx);
        const _Float16 ly = (_Float16)(qy - (float)hy);
        const _Float16 lz = (_Float16)(qz - (float)hz);
        const float sq = fmaf(qx, qx, fmaf(qy, qy, qz * qz));
        const _Float16 sh = (_Float16)sq;
        const _Float16 sl = (_Float16)(sq - (float)sh);

        const _Float16 nhx = (_Float16)(-2.0f * (float)hx);
        const _Float16 nhy = (_Float16)(-2.0f * (float)hy);
        const _Float16 nhz = (_Float16)(-2.0f * (float)hz);
        const _Float16 nlx = (_Float16)(-2.0f * (float)lx);
        const _Float16 nly = (_Float16)(-2.0f * (float)ly);
        const _Float16 nlz = (_Float16)(-2.0f * (float)lz);

        Bf[t * 64 + c]      = (half8){nhx, nhy, nhz, nlx, nly, nlz, nhx, nhy};
        Bf[t * 64 + 32 + c] = (half8){nhz, one, one, sh,  sl,  zz,  zz,  zz};
    }

    // ---- TWO A fragments (rows pbase+col, pbase+32+col) ----
    half8 a0, a1;
    #pragma unroll
    for (int h = 0; h < 2; ++h) {
        const float* P = Acl + ((size_t)b * NPTS + pbase + h * 32 + col) * 3;
        const float px = P[0], py = P[1], pz = P[2];
        const _Float16 hx = (_Float16)px, hy = (_Float16)py, hz = (_Float16)pz;
        const _Float16 lx = (_Float16)(px - (float)hx);
        const _Float16 ly = (_Float16)(py - (float)hy);
        const _Float16 lz = (_Float16)(pz - (float)hz);
        const float sq1 = fmaf(px, px, fmaf(py, py, pz * pz));
        const _Float16 sh = (_Float16)sq1;
        const _Float16 sl = (_Float16)(sq1 - (float)sh);
        half8 a;
        if (g == 0) a = (half8){hx, hy, hz, hx, hy, hz, lx, ly};
        else        a = (half8){lz, sh, sl, one, one, zz, zz, zz};
        if (h == 0) a0 = a; else a1 = a;
    }

    float rm0[16], rm1[16];
    #pragma unroll
    for (int r = 0; r < 16; ++r) { rm0[r] = 3.402823466e+38f;
                                   rm1[r] = 3.402823466e+38f; }

    __syncthreads();   // LDS build complete; read-only from here on

    // ---- unroll-2 positional double buffer; 16 STEP2s ----
    half8 pA0 = Bf[0 * 64 + lane], pA1 = Bf[1 * 64 + lane];
    half8 pB0, pB1;

    for (int t = 0; t < TPW; t += 4) {
        pB0 = Bf[(t + 2) * 64 + lane];     // prefetch during A's STEP2
        pB1 = Bf[(t + 3) * 64 + lane];
        STEP2(pA0, pA1);
        pA0 = Bf[(t + 4) * 64 + lane];     // prefetch during B's STEP2
        pA1 = Bf[(t + 5) * 64 + lane];     // (tail lands in the 2 pad tiles)
        STEP2(pB0, pB1);
    }

    // ---- epilogue: LDS block-reduce (replaces shfl_xor storm) ----
    __syncthreads();                       // all waves done reading Bf
    float* RB = (float*)Bf;                // 4 waves x 2 h x 16 r x 64 lanes
    #pragma unroll
    for (int r = 0; r < 16; ++r) {
        RB[((w * 2 + 0) * 16 + r) * 64 + lane] = rm0[r];
        RB[((w * 2 + 1) * 16 + r) * 64 + lane] = rm1[r];
    }
    __syncthreads();

    // one thread per output row: tid -> (wave ww, half h, row R within 32)
    {
        const int ww = tid >> 6, h = (tid >> 5) & 1, R = tid & 31;
        const int r  = (R & 3) + 4 * (R >> 3);
        const int gg = (R >> 2) & 1;
        const float* src = RB + (((ww * 2 + h) * 16 + r) * 64 + gg * 32);
        float m0 = fminf(src[0], src[1]);
        #pragma unroll
        for (int k = 2; k < 32; k += 2)
            m0 = fminf(m0, fminf(src[k], src[k + 1]));
        // coalesced store: block's 256 rows are contiguous
        const size_t obase = (((size_t)dir * NB + b) * SPLITS + qs) * NPTS
                             + (size_t)pt * 256;
        ws_row[obase + ww * 64 + h * 32 + R] = m0;
    }
}

// ---------- reduce: 256 blocks; min over 8 splits, block partial sums ----------
__global__ __launch_bounds__(256) void chamfer_reduce(
    const float* __restrict__ ws_row, float* __restrict__ partial)
{
    int bid = blockIdx.x;                    // 2 dir x 4 b x 32 slices
    const int sl  = bid & 31; bid >>= 5;
    const int b   = bid & 3;  bid >>= 2;
    const int dir = bid;

    const int p = sl * 256 + threadIdx.x;
    const float* base = ws_row + (((size_t)dir * NB + b) * SPLITS) * NPTS + p;
    float m0 = fminf(base[0],        base[NPTS]);
    float m1 = fminf(base[2 * NPTS], base[3 * NPTS]);
    float m2 = fminf(base[4 * NPTS], base[5 * NPTS]);
    float m3 = fminf(base[6 * NPTS], base[7 * NPTS]);
    float sum = fminf(fminf(m0, m1), fminf(m2, m3));

    for (int off = 32; off; off >>= 1) sum += __shfl_down(sum, off, 64);
    __shared__ float red[4];
    if (!(threadIdx.x & 63)) red[threadIdx.x >> 6] = sum;
    __syncthreads();
    if (!threadIdx.x)
        partial[blockIdx.x] = red[0] + red[1] + red[2] + red[3];
}

// ---------- final: 4 blocks x 64 thr; each b sums its 64 partials ----------
__global__ __launch_bounds__(64) void chamfer_final(
    const float* __restrict__ partial, float* __restrict__ out)
{
    const int b = blockIdx.x, t = threadIdx.x;
    const int dir = t >> 5, sl = t & 31;
    float v = partial[(((size_t)dir * NB + b) << 5) + sl];
    for (int off = 32; off; off >>= 1) v += __shfl_down(v, off, 64);
    if (!t) out[b] = v * (1.0f / (float)NPTS);
}

extern "C" void kernel_launch(void* const* d_in, const int* in_sizes, int n_in,
                              void* d_out, int out_size, void* d_ws, size_t ws_size,
                              hipStream_t stream)
{
    const float* pc1 = (const float*)d_in[0];
    const float* pc2 = (const float*)d_in[1];
    float* out = (float*)d_out;

    char* ws = (char*)d_ws;
    float* ws_row  = (float*)ws;                // 2*4*8*8192*4B = 2 MiB
    float* partial = (float*)(ws + (2 << 20));  // 1 KiB

    chamfer_main<<<2048, 256, 0, stream>>>(pc1, pc2, ws_row);
    chamfer_reduce<<<256, 256, 0, stream>>>(ws_row, partial);
    chamfer_final<<<NB, 64, 0, stream>>>(partial, out);
}

// Round 18
// 27.110 us; speedup vs baseline: 4.6300x; 1.0238x over previous
//
#include <hip/hip_runtime.h>

// Chamfer distance, B=4, N=8192, fp32 3-D points, MI355X.
// Round 18: r17 (2 A-frags/wave + LDS block-reduce epilogue, 27.8us) with
// the inner loop's nop walls replaced by the r12 rotation -- now valid
// because r16 removed the shuttled operands (zero16, ring movs):
//   per B-pair: {MFMA x=a0x(q0,q1)} {fold rm1<-y_prev} {MFMA y=a1x(q0,q1)}
//               {fold rm0<-x}
//   every MFMA->VALU-read distance >= 80 cyc of useful work (fold 64 +
//   MFMA issue 16) -> ZERO s_nops in steady state (one wall in the peel).
//   WAR (fold reads y, next MFMA rewrites y) is safe: VALU reads at issue.
// K-slot packing (verified r3-r17):
//   A g0={hx,hy,hz,hx,hy,hz,lx,ly}  g1={lz,sh,sl,1,1,0,0,0}
//   B g0={-2hx,-2hy,-2hz,-2lx,-2ly,-2lz,-2hx,-2hy}  g1={-2hz,1,1,sh,sl,0,0,0}

typedef _Float16 half8  __attribute__((ext_vector_type(8)));
typedef float    f32x16 __attribute__((ext_vector_type(16)));

#define NPTS   8192
#define NB     4
#define SPLITS 8
#define TPW    32                  // B-tiles per window
#define QWIN   (TPW * 32)          // 1024 q-points per window

#define MFMA_Z(d, a, b)                                                \
    asm("v_mfma_f32_32x32x16_f16 %0, %1, %2, 0"                        \
        : "=&v"(d) : "v"(a), "v"(b))

#define MIN3(dst, s0, s1)                                              \
    asm("v_min3_f32 %0, %1, %2, %0"                                    \
        : "+v"(dst) : "v"(s0), "v"(s1))

#define SB() __builtin_amdgcn_sched_barrier(0)

// rotation body: one B-pair vs both A-frags, zero nops
#define PAIR_ROT(q0, q1)                                               \
    do {                                                               \
        MFMA_Z(x0, a0, q0);                                            \
        MFMA_Z(x1, a0, q1);                                            \
        SB();                                                          \
        _Pragma("unroll")                                              \
        for (int r = 0; r < 16; ++r) MIN3(rm1[r], y0[r], y1[r]);       \
        SB();                                                          \
        MFMA_Z(y0, a1, q0);                                            \
        MFMA_Z(y1, a1, q1);                                            \
        SB();                                                          \
        _Pragma("unroll")                                              \
        for (int r = 0; r < 16; ++r) MIN3(rm0[r], x0[r], x1[r]);       \
        SB();                                                          \
    } while (0)

// ---------- main: 2048 blocks x 256 thr (4 waves) ----------
// block = (dir, b, qsplit-of-8, ptile-of-256); wave = 64 p-rows (2 A-tiles).
__global__ __launch_bounds__(256) void chamfer_main(
    const float* __restrict__ pc1, const float* __restrict__ pc2,
    float* __restrict__ ws_row)
{
    // Bf: fragment window (34 KiB); reused after the loop as the 32 KiB
    // block-reduction buffer.
    __shared__ half8 Bf[(TPW + 2) * 64];

    int bid = blockIdx.x;
    const int pt  = bid & 31;            bid >>= 5;
    const int qs  = bid & (SPLITS - 1);  bid >>= 3;
    const int b   = bid & (NB - 1);      bid >>= 2;
    const int dir = bid;

    const int tid = threadIdx.x;
    const int w = tid >> 6, lane = tid & 63;
    const int col = lane & 31, g = lane >> 5;
    const int pbase = pt * 256 + w * 64;       // this wave: rows pbase..pbase+63

    const float* Acl = dir ? pc2 : pc1;        // row side
    const float* Bcl = dir ? pc1 : pc2;        // col side

    const _Float16 one = (_Float16)1.0f, zz = (_Float16)0.0f;

    // ---- build this block's B-fragment window in LDS (4 points/thread) ----
    for (int i = tid; i < QWIN; i += 256) {
        const int t = i >> 5, c = i & 31;
        const float* Q = Bcl + ((size_t)b * NPTS + qs * QWIN + i) * 3;
        const float qx = Q[0], qy = Q[1], qz = Q[2];

        const _Float16 hx = (_Float16)qx, hy = (_Float16)qy, hz = (_Float16)qz;
        const _Float16 lx = (_Float16)(qx - (float)hx);
        const _Float16 ly = (_Float16)(qy - (float)hy);
        const _Float16 lz = (_Float16)(qz - (float)hz);
        const float sq = fmaf(qx, qx, fmaf(qy, qy, qz * qz));
        const _Float16 sh = (_Float16)sq;
        const _Float16 sl = (_Float16)(sq - (float)sh);

        const _Float16 nhx = (_Float16)(-2.0f * (float)hx);
        const _Float16 nhy = (_Float16)(-2.0f * (float)hy);
        const _Float16 nhz = (_Float16)(-2.0f * (float)hz);
        const _Float16 nlx = (_Float16)(-2.0f * (float)lx);
        const _Float16 nly = (_Float16)(-2.0f * (float)ly);
        const _Float16 nlz = (_Float16)(-2.0f * (float)lz);

        Bf[t * 64 + c]      = (half8){nhx, nhy, nhz, nlx, nly, nlz, nhx, nhy};
        Bf[t * 64 + 32 + c] = (half8){nhz, one, one, sh,  sl,  zz,  zz,  zz};
    }

    // ---- TWO A fragments (rows pbase+col, pbase+32+col) ----
    half8 a0, a1;
    #pragma unroll
    for (int h = 0; h < 2; ++h) {
        const float* P = Acl + ((size_t)b * NPTS + pbase + h * 32 + col) * 3;
        const float px = P[0], py = P[1], pz = P[2];
        const _Float16 hx = (_Float16)px, hy = (_Float16)py, hz = (_Float16)pz;
        const _Float16 lx = (_Float16)(px - (float)hx);
        const _Float16 ly = (_Float16)(py - (float)hy);
        const _Float16 lz = (_Float16)(pz - (float)hz);
        const float sq1 = fmaf(px, px, fmaf(py, py, pz * pz));
        const _Float16 sh = (_Float16)sq1;
        const _Float16 sl = (_Float16)(sq1 - (float)sh);
        half8 a;
        if (g == 0) a = (half8){hx, hy, hz, hx, hy, hz, lx, ly};
        else        a = (half8){lz, sh, sl, one, one, zz, zz, zz};
        if (h == 0) a0 = a; else a1 = a;
    }

    float rm0[16], rm1[16];
    #pragma unroll
    for (int r = 0; r < 16; ++r) { rm0[r] = 3.402823466e+38f;
                                   rm1[r] = 3.402823466e+38f; }

    __syncthreads();   // LDS build complete; read-only until the next barrier

    half8 pA0 = Bf[0 * 64 + lane], pA1 = Bf[1 * 64 + lane];
    half8 pB0 = Bf[2 * 64 + lane], pB1 = Bf[3 * 64 + lane];
    f32x16 x0, x1, y0, y1;

    // ---- peeled pair 0 (tiles 0,1): no y_prev yet -> one nop wall ----
    MFMA_Z(x0, a0, pA0);
    MFMA_Z(x1, a0, pA1);
    SB();
    asm volatile("s_nop 7\n\ts_nop 7\n\ts_nop 3");
    SB();
    MFMA_Z(y0, a1, pA0);
    MFMA_Z(y1, a1, pA1);
    SB();
    #pragma unroll
    for (int r = 0; r < 16; ++r) MIN3(rm0[r], x0[r], x1[r]);
    SB();
    pA0 = Bf[4 * 64 + lane];
    pA1 = Bf[5 * 64 + lane];

    // ---- pairs 1..14 (7 iters x 2 pairs), zero nops ----
    for (int j = 0; j < 7; ++j) {
        PAIR_ROT(pB0, pB1);
        pB0 = Bf[(6 + 4 * j) * 64 + lane];
        pB1 = Bf[(7 + 4 * j) * 64 + lane];
        PAIR_ROT(pA0, pA1);
        pA0 = Bf[(8 + 4 * j) * 64 + lane];   // j=6 -> tiles 32,33 (pad, unused)
        pA1 = Bf[(9 + 4 * j) * 64 + lane];
    }

    // ---- final pair 15 (tiles 30,31) + epilogue fold of the last y ----
    PAIR_ROT(pB0, pB1);
    #pragma unroll
    for (int r = 0; r < 16; ++r) MIN3(rm1[r], y0[r], y1[r]);

    // ---- epilogue: LDS block-reduce + coalesced store (r17 pattern) ----
    __syncthreads();                       // all waves done reading Bf
    float* RB = (float*)Bf;                // 4 waves x 2 h x 16 r x 64 lanes
    #pragma unroll
    for (int r = 0; r < 16; ++r) {
        RB[((w * 2 + 0) * 16 + r) * 64 + lane] = rm0[r];
        RB[((w * 2 + 1) * 16 + r) * 64 + lane] = rm1[r];
    }
    __syncthreads();

    {
        const int ww = tid >> 6, h = (tid >> 5) & 1, R = tid & 31;
        const int r  = (R & 3) + 4 * (R >> 3);
        const int gg = (R >> 2) & 1;
        const float* src = RB + (((ww * 2 + h) * 16 + r) * 64 + gg * 32);
        float m0 = fminf(src[0], src[1]);
        #pragma unroll
        for (int k = 2; k < 32; k += 2)
            m0 = fminf(m0, fminf(src[k], src[k + 1]));
        const size_t obase = (((size_t)dir * NB + b) * SPLITS + qs) * NPTS
                             + (size_t)pt * 256;
        ws_row[obase + ww * 64 + h * 32 + R] = m0;
    }
}

// ---------- reduce: 256 blocks; min over 8 splits, block partial sums ----------
__global__ __launch_bounds__(256) void chamfer_reduce(
    const float* __restrict__ ws_row, float* __restrict__ partial)
{
    int bid = blockIdx.x;                    // 2 dir x 4 b x 32 slices
    const int sl  = bid & 31; bid >>= 5;
    const int b   = bid & 3;  bid >>= 2;
    const int dir = bid;

    const int p = sl * 256 + threadIdx.x;
    const float* base = ws_row + (((size_t)dir * NB + b) * SPLITS) * NPTS + p;
    float m0 = fminf(base[0],        base[NPTS]);
    float m1 = fminf(base[2 * NPTS], base[3 * NPTS]);
    float m2 = fminf(base[4 * NPTS], base[5 * NPTS]);
    float m3 = fminf(base[6 * NPTS], base[7 * NPTS]);
    float sum = fminf(fminf(m0, m1), fminf(m2, m3));

    for (int off = 32; off; off >>= 1) sum += __shfl_down(sum, off, 64);
    __shared__ float red[4];
    if (!(threadIdx.x & 63)) red[threadIdx.x >> 6] = sum;
    __syncthreads();
    if (!threadIdx.x)
        partial[blockIdx.x] = red[0] + red[1] + red[2] + red[3];
}

// ---------- final: 4 blocks x 64 thr; each b sums its 64 partials ----------
__global__ __launch_bounds__(64) void chamfer_final(
    const float* __restrict__ partial, float* __restrict__ out)
{
    const int b = blockIdx.x, t = threadIdx.x;
    const int dir = t >> 5, sl = t & 31;
    float v = partial[(((size_t)dir * NB + b) << 5) + sl];
    for (int off = 32; off; off >>= 1) v += __shfl_down(v, off, 64);
    if (!t) out[b] = v * (1.0f / (float)NPTS);
}

extern "C" void kernel_launch(void* const* d_in, const int* in_sizes, int n_in,
                              void* d_out, int out_size, void* d_ws, size_t ws_size,
                              hipStream_t stream)
{
    const float* pc1 = (const float*)d_in[0];
    const float* pc2 = (const float*)d_in[1];
    float* out = (float*)d_out;

    char* ws = (char*)d_ws;
    float* ws_row  = (float*)ws;                // 2*4*8*8192*4B = 2 MiB
    float* partial = (float*)(ws + (2 << 20));  // 1 KiB

    chamfer_main<<<2048, 256, 0, stream>>>(pc1, pc2, ws_row);
    chamfer_reduce<<<256, 256, 0, stream>>>(ws_row, partial);
    chamfer_final<<<NB, 64, 0, stream>>>(partial, out);
}